// Round 4
// baseline (142056.030 us; speedup 1.0000x reference)
//
#include <hip/hip_runtime.h>
#include <stdint.h>

// FPS: B=32, C=3, N=131072, M=2048, f32.
// 32 batches x 8 WGs x 1024 threads; 16 points/thread in registers.
// Round 2 design: u64 sortable keys, tag-based release/poll barrier, 1 syncthreads/iter.

#define B_   32
#define N_   131072
#define M_   2048
#define WPB  8          // workgroups per batch
#define T_   1024       // threads per workgroup
#define PTS  16         // points per thread
#define ITERS (M_ - 1)
#define NPW  (N_ / WPB) // 16384 points per WG

typedef unsigned long long u64;

__global__ void __launch_bounds__(T_, 4)
fps_main(const float* __restrict__ x, float* __restrict__ y,
         unsigned* __restrict__ recs) {
    const int bid  = blockIdx.x;
    const int b    = bid & (B_ - 1);  // batch; WGs of a batch share bid%8 -> same XCD under round-robin (perf only)
    const int wl   = bid >> 5;        // 0..7 wg-local id within batch
    const int tid  = threadIdx.x;
    const int lane = tid & 63;
    const int wave = tid >> 6;

    const float* __restrict__ xb = x + (size_t)b * 3u * N_;
    float* __restrict__ yb = y + (size_t)b * 3u * M_;
    const unsigned pbase = (unsigned)(wl * NPW + tid);

    // register-resident coords + running min-dists
    float X[PTS], Y[PTS], Z[PTS], D[PTS];
#pragma unroll
    for (int k = 0; k < PTS; ++k) {
        unsigned p = pbase + (unsigned)(k * T_);
        X[k] = xb[p];
        Y[k] = xb[N_ + p];
        Z[k] = xb[2 * N_ + p];
        D[k] = INFINITY;
    }

    float lx = xb[0], ly = xb[N_], lz = xb[2 * N_];
    if (wl == 0 && tid == 0) { yb[0] = lx; yb[M_] = ly; yb[2 * M_] = lz; }

    __shared__ u64   s_key[2][16];
    __shared__ float s_cx[2][16], s_cy[2][16], s_cz[2][16];

    // record: 8 dwords: [0]=key_lo [1]=key_hi [2]=x [3]=y [4]=z [5,6]=pad [7]=tag
    // recs layout: [batch][parity][WPB][8] u32

    for (int it = 0; it < ITERS; ++it) {
        const int par = it & 1;

        // ---- update min-dists + thread-local best (strict > keeps lowest idx) ----
        float bv = -INFINITY; unsigned bi = 0u;
#pragma unroll
        for (int k = 0; k < PTS; ++k) {
            float dx = X[k] - lx;
            float dy = Y[k] - ly;
            float dz = Z[k] - lz;
            // match XLA rounding: ((dx*dx)+(dy*dy))+(dz*dz), no FMA contraction
            float d  = __fadd_rn(__fadd_rn(__fmul_rn(dx, dx), __fmul_rn(dy, dy)),
                                 __fmul_rn(dz, dz));
            float nd = fminf(D[k], d);
            D[k] = nd;
            bool t = nd > bv;
            bv = t ? nd : bv;
            bi = t ? (pbase + (unsigned)(k * T_)) : bi;
        }

        // sortable unique key: dist bits high (d>=0 so bits are order-preserving),
        // ~idx low (ties -> lower index wins, matching jnp.argmax-first)
        u64 key = ((u64)__float_as_uint(bv) << 32) | (u64)(~bi);

        // ---- wave butterfly max (key-only; 2 bpermutes/level) ----
        u64 wk = key;
#pragma unroll
        for (int off = 1; off < 64; off <<= 1) {
            u64 o = __shfl_xor(wk, off);
            wk = (o > wk) ? o : wk;
        }

        // exactly one lane matches (keys unique): it deposits coords to LDS
        if (key == wk) {
            float bx = 0.f, by = 0.f, bz = 0.f;
#pragma unroll
            for (int k = 0; k < PTS; ++k)
                if (pbase + (unsigned)(k * T_) == bi) { bx = X[k]; by = Y[k]; bz = Z[k]; }
            s_key[par][wave] = wk;
            s_cx[par][wave] = bx; s_cy[par][wave] = by; s_cz[par][wave] = bz;
        }
        __syncthreads();   // the ONLY block barrier per iteration

        // ---- wave0 combines 16 wave-winners and publishes the WG record ----
        if (wave == 0) {
            u64 k2 = (lane < 16) ? s_key[par][lane] : 0ull;
            u64 m2 = k2;
#pragma unroll
            for (int off = 1; off < 16; off <<= 1) {
                u64 o = __shfl_xor(m2, off);
                m2 = (o > m2) ? o : m2;
            }
            if (lane < 16 && k2 == m2) {
                unsigned* r = recs + (size_t)(((b * 2 + par) * WPB + wl) * 8);
                r[0] = (unsigned)(k2 & 0xFFFFFFFFull);
                r[1] = (unsigned)(k2 >> 32);
                ((float*)r)[2] = s_cx[par][lane];
                ((float*)r)[3] = s_cy[par][lane];
                ((float*)r)[4] = s_cz[par][lane];
                // release: prior stores visible before tag
                __hip_atomic_store(&r[7], (unsigned)(it + 1),
                                   __ATOMIC_RELEASE, __HIP_MEMORY_SCOPE_AGENT);
            }
        }

        // ---- all 16 waves poll the 8 tags directly (no counter, no 2nd barrier) ----
        unsigned* rb = recs + (size_t)((b * 2 + par) * WPB * 8);
        const unsigned want = (unsigned)(it + 1);
        for (;;) {
            unsigned t = want;
            if (lane < WPB)
                t = __hip_atomic_load(&rb[lane * 8 + 7],
                                      __ATOMIC_RELAXED, __HIP_MEMORY_SCOPE_AGENT);
            if (__all(t == want)) break;
            __builtin_amdgcn_s_sleep(1);
        }
        __threadfence();  // acquire: record bodies ordered after observed tags

        // ---- every lane reduces the 8 records redundantly (broadcast loads) ----
        u64 bk = 0ull; float wx = 0.f, wy = 0.f, wz = 0.f;
#pragma unroll
        for (int r = 0; r < WPB; ++r) {
            unsigned lo = __hip_atomic_load(&rb[r * 8 + 0], __ATOMIC_RELAXED, __HIP_MEMORY_SCOPE_AGENT);
            unsigned hi = __hip_atomic_load(&rb[r * 8 + 1], __ATOMIC_RELAXED, __HIP_MEMORY_SCOPE_AGENT);
            unsigned cx = __hip_atomic_load(&rb[r * 8 + 2], __ATOMIC_RELAXED, __HIP_MEMORY_SCOPE_AGENT);
            unsigned cy = __hip_atomic_load(&rb[r * 8 + 3], __ATOMIC_RELAXED, __HIP_MEMORY_SCOPE_AGENT);
            unsigned cz = __hip_atomic_load(&rb[r * 8 + 4], __ATOMIC_RELAXED, __HIP_MEMORY_SCOPE_AGENT);
            u64 k3 = ((u64)hi << 32) | (u64)lo;
            bool take = k3 > bk;
            bk = take ? k3 : bk;
            wx = take ? __uint_as_float(cx) : wx;
            wy = take ? __uint_as_float(cy) : wy;
            wz = take ? __uint_as_float(cz) : wz;
        }
        lx = wx; ly = wy; lz = wz;

        if (wl == 0 && tid == 0) {
            yb[it + 1]          = lx;
            yb[M_ + it + 1]     = ly;
            yb[2 * M_ + it + 1] = lz;
        }
    }
}

extern "C" void kernel_launch(void* const* d_in, const int* in_sizes, int n_in,
                              void* d_out, int out_size, void* d_ws, size_t ws_size,
                              hipStream_t stream) {
    const float* x = (const float*)d_in[0];
    float* y = (float*)d_out;
    unsigned* recs = (unsigned*)d_ws;  // 32*2*8*8 u32 = 16 KiB
    // no init kernel needed: tag protocol is exact-match on it+1; the harness
    // re-poisons d_ws to 0xAA before every launch, and 0xAAAAAAAA never
    // matches a wanted tag in [1, 2047].
    fps_main<<<B_ * WPB, T_, 0, stream>>>(x, y, recs);
}

// Round 5
// 5578.598 us; speedup vs baseline: 25.4645x; 25.4645x over previous
//
#include <hip/hip_runtime.h>
#include <stdint.h>

// FPS: B=32, C=3, N=131072, M=2048, f32.
// Round 4: fence-free exchange. Winner communicated as ONE relaxed u64
// (dist | iter-tag | ~idx); coords re-read from immutable x by index, so no
// acquire/release is needed anywhere. Only wave 0 polls (256 pollers total).

#define B_   32
#define N_   131072
#define M_   2048
#define WPB  8          // workgroups per batch
#define T_   1024       // threads per workgroup
#define PTS  16         // points per thread
#define ITERS (M_ - 1)
#define NPW  (N_ / WPB) // 16384 points per WG

typedef unsigned long long u64;

__global__ void __launch_bounds__(T_, 4)
fps_main(const float* __restrict__ x, float* __restrict__ y,
         u64* __restrict__ slots) {
    const int bid  = blockIdx.x;
    const int b    = bid & (B_ - 1);  // batch id; 8 WGs/batch
    const int wl   = bid >> 5;        // wg-local id 0..7
    const int tid  = threadIdx.x;
    const int lane = tid & 63;
    const int wave = tid >> 6;

    const float* __restrict__ xb = x + (size_t)b * 3u * N_;
    float* __restrict__ yb = y + (size_t)b * 3u * M_;
    const unsigned pbase = (unsigned)(wl * NPW + tid);

    // register-resident coords + running min-dists (64 VGPRs of state)
    float X[PTS], Y[PTS], Z[PTS], D[PTS];
#pragma unroll
    for (int k = 0; k < PTS; ++k) {
        unsigned p = pbase + (unsigned)(k * T_);
        X[k] = xb[p];
        Y[k] = xb[N_ + p];
        Z[k] = xb[2 * N_ + p];
        D[k] = INFINITY;
    }

    float lx = xb[0], ly = xb[N_], lz = xb[2 * N_];
    if (wl == 0 && tid == 0) { yb[0] = lx; yb[M_] = ly; yb[2 * M_] = lz; }

    __shared__ u64   s_key[16];
    __shared__ float s_c[3];     // winner coords

    // slots layout: [batch][parity][WPB] u64 (8 slots = one 64B line)

    for (int it = 0; it < ITERS; ++it) {
        const int par = it & 1;

        // ---- update min-dists + thread-local best (strict > keeps lowest idx) ----
        float bv = -INFINITY; unsigned bi = 0u;
#pragma unroll
        for (int k = 0; k < PTS; ++k) {
            float dx = X[k] - lx;
            float dy = Y[k] - ly;
            float dz = Z[k] - lz;
            // match XLA rounding: ((dx*dx)+(dy*dy))+(dz*dz), no FMA contraction
            float d  = __fadd_rn(__fadd_rn(__fmul_rn(dx, dx), __fmul_rn(dy, dy)),
                                 __fmul_rn(dz, dz));
            float nd = fminf(D[k], d);
            D[k] = nd;
            bool t = nd > bv;
            bv = t ? nd : bv;
            bi = t ? (pbase + (unsigned)(k * T_)) : bi;
        }

        // key: [dist:32 | tag(it):15 | (0x1FFFF - idx):17]
        // tag bits are equal across all WGs within an iteration, so ordering is
        // dist-major then lowest-index (jnp.argmax first-match semantics).
        // 0xAAAA.. poison tag = 0x5555, stale-replay tags = 2045/2046 -> never
        // equal to a wanted tag at the same parity. No init kernel needed.
        u64 key = ((u64)__float_as_uint(bv) << 32)
                | ((u64)(unsigned)it << 17)
                | (u64)(0x1FFFFu - bi);

        // ---- wave butterfly max ----
#pragma unroll
        for (int off = 1; off < 64; off <<= 1) {
            u64 o = __shfl_xor(key, off);
            key = (o > key) ? o : key;
        }
        if (lane == 0) s_key[wave] = key;
        __syncthreads();

        // ---- wave 0: combine 16 wave-winners, publish, poll, fetch coords ----
        if (wave == 0) {
            u64 k2 = (lane < 16) ? s_key[lane] : 0ull;
#pragma unroll
            for (int off = 1; off < 16; off <<= 1) {
                u64 o = __shfl_xor(k2, off);
                k2 = (o > k2) ? o : k2;
            }

            u64* base = slots + (size_t)((b * 2 + par) * WPB);
            if (lane == 0)
                __hip_atomic_store(base + wl, k2,
                                   __ATOMIC_RELAXED, __HIP_MEMORY_SCOPE_AGENT);

            // poll the 8 slots (one 64B line, coalesced, relaxed, no fences)
            const unsigned wtag = (unsigned)it;
            u64 got = 0ull;
            for (;;) {
                if (lane < WPB)
                    got = __hip_atomic_load(base + lane,
                                            __ATOMIC_RELAXED, __HIP_MEMORY_SCOPE_AGENT);
                bool ok = (lane >= WPB) | (((unsigned)(got >> 17) & 0x7FFFu) == wtag);
                if (__all(ok)) break;
                __builtin_amdgcn_s_sleep(2);
            }

            // batch winner = max of the 8 slot keys
            u64 w = (lane < WPB) ? got : 0ull;
#pragma unroll
            for (int off = 1; off < 8; off <<= 1) {
                u64 o = __shfl_xor(w, off);
                w = (o > w) ? o : w;
            }
            unsigned widx = 0x1FFFFu - (unsigned)(w & 0x1FFFFu);
            // coords from the immutable input: no ordering needed
            if (lane < 3) s_c[lane] = xb[(size_t)lane * N_ + widx];
        }
        __syncthreads();

        lx = s_c[0]; ly = s_c[1]; lz = s_c[2];
        if (wl == 0 && tid == 0) {
            yb[it + 1]          = lx;
            yb[M_ + it + 1]     = ly;
            yb[2 * M_ + it + 1] = lz;
        }
    }
}

extern "C" void kernel_launch(void* const* d_in, const int* in_sizes, int n_in,
                              void* d_out, int out_size, void* d_ws, size_t ws_size,
                              hipStream_t stream) {
    const float* x = (const float*)d_in[0];
    float* y = (float*)d_out;
    u64* slots = (u64*)d_ws;   // 32 * 2 * 8 u64 = 4 KiB
    fps_main<<<B_ * WPB, T_, 0, stream>>>(x, y, slots);
}